// Round 1
// baseline (452.441 us; speedup 1.0000x reference)
//
#include <hip/hip_runtime.h>
#include <hip/hip_bf16.h>

// AutoCorrelation layer: QKV proj (bf16x3 MFMA GEMM) -> packed FFT cross-corr
// -> top-8 + softmax -> delay-gather of V -> output proj.
// B=4, L=4096, D_MODEL=512, NHEAD=8, DH=64, TOPK=8.

#define MiB (1024ull * 1024ull)

typedef __attribute__((ext_vector_type(8))) short bf16x8;
typedef __attribute__((ext_vector_type(4))) float f32x4;
static_assert(sizeof(bf16x8) == 16, "bf16x8 must be 16B");

__device__ __forceinline__ unsigned short f2bf(float f) {
  unsigned u = __float_as_uint(f);
  unsigned r = (u + 0x7FFFu + ((u >> 16) & 1u)) >> 16;  // RN-even
  return (unsigned short)r;
}
__device__ __forceinline__ float bf2f(unsigned short h) {
  return __uint_as_float(((unsigned)h) << 16);
}
// base-4 digit reversal of a 12-bit index (involution)
__device__ __forceinline__ int rev4_12(int x) {
  unsigned r = __brev((unsigned)x) >> 20;
  return (int)(((r & 0xAAAu) >> 1) | ((r & 0x555u) << 1));
}
// LDS pad: +1 float per 32 to break power-of-2 bank patterns
#define IDX(e) ((e) + ((e) >> 5))
#define LDSN (4095 + (4095 >> 5) + 1)

// ---------------- conversion kernels ----------------

// x (f32) -> hi/lo bf16 split (A = hi + lo exactly to ~16 mantissa bits)
__global__ void conv_split(const float* __restrict__ x, unsigned short* __restrict__ hi,
                           unsigned short* __restrict__ lo, int n4) {
  int i = blockIdx.x * 256 + threadIdx.x;
  if (i >= n4) return;
  float4 v = ((const float4*)x)[i];
  ushort4 h, l;
  float f;
  f = v.x; h.x = f2bf(f); l.x = f2bf(f - bf2f(h.x));
  f = v.y; h.y = f2bf(f); l.y = f2bf(f - bf2f(h.y));
  f = v.z; h.z = f2bf(f); l.z = f2bf(f - bf2f(h.z));
  f = v.w; h.w = f2bf(f); l.w = f2bf(f - bf2f(h.w));
  ((ushort4*)hi)[i] = h;
  ((ushort4*)lo)[i] = l;
}

// W (512x512 f32, [k][n]) -> transposed hi/lo bf16 Wt[n][k]
__global__ void conv_wt(const float* __restrict__ W, unsigned short* __restrict__ hi,
                        unsigned short* __restrict__ lo) {
  int idx = blockIdx.x * 256 + threadIdx.x;  // 262144
  int n = idx >> 9, k = idx & 511;
  float f = W[k * 512 + n];
  unsigned short h = f2bf(f);
  hi[idx] = h;
  lo[idx] = f2bf(f - bf2f(h));
}

// twiddle table T[r] = exp(-2*pi*i*r/4096), r=0..3071 (double-precision generated)
__global__ void make_tw(float2* __restrict__ T) {
  int r = blockIdx.x * 256 + threadIdx.x;
  if (r < 3072) {
    double a = -2.0 * 3.14159265358979323846 * (double)r / 4096.0;
    T[r] = make_float2((float)cos(a), (float)sin(a));
  }
}

// ---------------- GEMM: C(16384x512) = A(16384x512) @ W(512x512) + bias ----------------
// bf16x3 split: segments [Ahi*Bhi, Ahi*Blo, Alo*Bhi] (nseg=3) or plain hi*hi (nseg=1).
// B is pre-transposed: Bt[n][k]. 128x128 tile, BK=64, 4 waves (2x2), mfma 16x16x32.
// mode 0: C[(b*512+n)*4096 + t]   (Q^T/K^T layout, float4 stores along t)
// mode 1: C[((b*8+h)*4096+t)*64+d] (V layout, n = h*64+d)
// mode 2: C[m*512+n]               (row-major output)
__global__ __launch_bounds__(256, 2)
void gemm_bf16(const unsigned short* __restrict__ Ahi, const unsigned short* __restrict__ Alo,
               const unsigned short* __restrict__ Bhi, const unsigned short* __restrict__ Blo,
               const float* __restrict__ bias, float* __restrict__ C,
               int nseg, int mode) {
  __shared__ short As[128 * 64];
  __shared__ short Bs[128 * 64];
  int bx = blockIdx.x;
  int bm = bx >> 2, bn = bx & 3;
  int m0 = bm << 7, n0 = bn << 7;
  int tid = threadIdx.x;
  int lane = tid & 63, wv = tid >> 6;
  int wm = wv >> 1, wn = wv & 1;

  const f32x4 zz = {0.f, 0.f, 0.f, 0.f};
  f32x4 acc[4][4];
#pragma unroll
  for (int i = 0; i < 4; ++i)
#pragma unroll
    for (int j = 0; j < 4; ++j) acc[i][j] = zz;

  int srow = tid >> 3;          // 0..31 (row within 32-row chunk)
  int sk = (tid & 7) << 3;      // 0..56 (k offset, 8 elems = 16B)
  int nks = nseg << 3;          // K-steps of 64 within each 512-segment
  for (int ks = 0; ks < nks; ++ks) {
    int seg = ks >> 3;
    int kb = (ks & 7) << 6;
    const unsigned short* Aseg = (seg == 2) ? Alo : Ahi;
    const unsigned short* Bseg = (seg == 1) ? Blo : Bhi;
#pragma unroll
    for (int i = 0; i < 4; ++i) {
      int r = (i << 5) + srow;
      const unsigned short* ga = Aseg + (size_t)(m0 + r) * 512 + kb + sk;
      const unsigned short* gb = Bseg + (size_t)(n0 + r) * 512 + kb + sk;
      char* la = (char*)As + (i << 12) + (wv << 10);  // wave-uniform LDS base
      char* lb = (char*)Bs + (i << 12) + (wv << 10);
      __builtin_amdgcn_global_load_lds((const __attribute__((address_space(1))) void*)ga,
                                       (__attribute__((address_space(3))) void*)la, 16, 0, 0);
      __builtin_amdgcn_global_load_lds((const __attribute__((address_space(1))) void*)gb,
                                       (__attribute__((address_space(3))) void*)lb, 16, 0, 0);
    }
    __syncthreads();
#pragma unroll
    for (int kk = 0; kk < 2; ++kk) {
      bf16x8 af[4], bfr[4];
      int krd = (kk << 5) + ((lane >> 4) << 3);
#pragma unroll
      for (int mi = 0; mi < 4; ++mi)
        af[mi] = *(const bf16x8*)&As[((wm << 6) + (mi << 4) + (lane & 15)) * 64 + krd];
#pragma unroll
      for (int ni = 0; ni < 4; ++ni)
        bfr[ni] = *(const bf16x8*)&Bs[((wn << 6) + (ni << 4) + (lane & 15)) * 64 + krd];
#pragma unroll
      for (int mi = 0; mi < 4; ++mi)
#pragma unroll
        for (int ni = 0; ni < 4; ++ni)
          acc[mi][ni] = __builtin_amdgcn_mfma_f32_16x16x32_bf16(af[mi], bfr[ni], acc[mi][ni], 0, 0, 0);
    }
    __syncthreads();
  }

  // epilogue: D lane l reg r -> row=(l>>4)*4+r, col=l&15 (per 16x16 fragment)
#pragma unroll
  for (int mi = 0; mi < 4; ++mi) {
    int mrow0 = m0 + (wm << 6) + (mi << 4) + ((lane >> 4) << 2);
    int bq = mrow0 >> 12;
    int t0 = mrow0 & 4095;
#pragma unroll
    for (int ni = 0; ni < 4; ++ni) {
      int col = n0 + (wn << 6) + (ni << 4) + (lane & 15);
      float bv = bias[col];
      f32x4 v = acc[mi][ni];
      v.x += bv; v.y += bv; v.z += bv; v.w += bv;
      if (mode == 0) {
        *(f32x4*)&C[((size_t)(bq * 512 + col)) * 4096 + t0] = v;
      } else if (mode == 1) {
        size_t base = (size_t)(bq * 8 + (col >> 6)) * 4096;
        int d = col & 63;
        C[(base + t0 + 0) * 64 + d] = v.x;
        C[(base + t0 + 1) * 64 + d] = v.y;
        C[(base + t0 + 2) * 64 + d] = v.z;
        C[(base + t0 + 3) * 64 + d] = v.w;
      } else {
        C[(size_t)(mrow0 + 0) * 512 + col] = v.x;
        C[(size_t)(mrow0 + 1) * 512 + col] = v.y;
        C[(size_t)(mrow0 + 2) * 512 + col] = v.z;
        C[(size_t)(mrow0 + 3) * 512 + col] = v.w;
      }
    }
  }
}

// ---------------- FFT: 6-stage radix-4 DIF (natural in -> digit-reversed out) ----------------
__device__ void dif_fft(float* re, float* im, const float2* __restrict__ TW, int tid) {
  int m = 1024, lm = 10;
#pragma unroll
  for (int s = 0; s < 6; ++s) {
    int stw = 1 << (2 * s);
    for (int bb = tid; bb < 1024; bb += 256) {
      int j = bb & (m - 1);
      int g = bb >> lm;
      int i0 = (g << (lm + 2)) + j;
      int p0 = IDX(i0), p1 = IDX(i0 + m), p2 = IDX(i0 + 2 * m), p3 = IDX(i0 + 3 * m);
      float are = re[p0], aim = im[p0];
      float cre = re[p1], cim = im[p1];
      float ere = re[p2], eim = im[p2];
      float gre = re[p3], gim = im[p3];
      float Are = are + ere, Aim = aim + eim;
      float Bre = are - ere, Bim = aim - eim;
      float Cre = cre + gre, Cim = cim + gim;
      float dre = cre - gre, dim_ = cim - gim;
      float Dre = dim_, Dim = -dre;  // -i*(c-g)
      re[p0] = Are + Cre; im[p0] = Aim + Cim;
      float2 w1 = TW[j * stw], w2 = TW[2 * j * stw], w3 = TW[3 * j * stw];
      float xr = Bre + Dre, xi = Bim + Dim;
      re[p1] = xr * w1.x - xi * w1.y; im[p1] = xr * w1.y + xi * w1.x;
      xr = Are - Cre; xi = Aim - Cim;
      re[p2] = xr * w2.x - xi * w2.y; im[p2] = xr * w2.y + xi * w2.x;
      xr = Bre - Dre; xi = Bim - Dim;
      re[p3] = xr * w3.x - xi * w3.y; im[p3] = xr * w3.y + xi * w3.x;
    }
    __syncthreads();
    m >>= 2; lm -= 2;
  }
}

// Packed FFT of z = q + i*k per (b,h,d); accumulate P[f] += Qf*conj(Kf) over d.
// One wg handles (b,h) x 4 d's; atomics merge the 16 wgs per (b,h).
__global__ __launch_bounds__(256, 2)
void fft_corr(const float* __restrict__ QT, const float* __restrict__ KT,
              const float2* __restrict__ TW, float* __restrict__ Pre, float* __restrict__ Pim) {
  __shared__ float re[LDSN];
  __shared__ float im[LDSN];
  __shared__ float pr[4096];
  __shared__ float pi[4096];
  int wg = blockIdx.x;
  int bh = wg >> 4;
  int d0 = (wg & 15) << 2;
  int tid = threadIdx.x;
  for (int e = tid; e < 4096; e += 256) { pr[e] = 0.f; pi[e] = 0.f; }
  const float* qb = QT + (size_t)bh * 64 * 4096;
  const float* kb = KT + (size_t)bh * 64 * 4096;
  for (int dd = 0; dd < 4; ++dd) {
    __syncthreads();  // prior S-phase reads of re/im done
    const float* q = qb + (size_t)(d0 + dd) * 4096;
    const float* k = kb + (size_t)(d0 + dd) * 4096;
    for (int e = tid; e < 4096; e += 256) {
      re[IDX(e)] = q[e];
      im[IDX(e)] = k[e];
    }
    __syncthreads();
    dif_fft(re, im, TW, tid);
    // position p holds Z[f], f = rev4(p); pair with f' = (N-f)%N at position rev4(f')
    for (int p = tid; p < 4096; p += 256) {
      int f = rev4_12(p);
      int fn = (4096 - f) & 4095;
      int pn = rev4_12(fn);
      float zr = re[IDX(p)], zi = im[IDX(p)];
      float wr = re[IDX(pn)], wi = im[IDX(pn)];
      float qre = 0.5f * (zr + wr), qim = 0.5f * (zi - wi);
      float kre = 0.5f * (zi + wi), kim = 0.5f * (wr - zr);
      pr[p] += qre * kre + qim * kim;   // Re(Qf*conj(Kf))
      pi[p] += qim * kre - qre * kim;   // Im(Qf*conj(Kf))
    }
  }
  __syncthreads();
  for (int p = tid; p < 4096; p += 256) {
    int f = rev4_12(p);
    atomicAdd(&Pre[bh * 4096 + f], pr[p]);
    atomicAdd(&Pim[bh * 4096 + f], pi[p]);
  }
}

// Inverse FFT via conj + forward DIF; corr(tau=rev4(p)) = re[p]/(4096*64). Then top-8 + softmax.
__global__ __launch_bounds__(256, 2)
void ifft_topk(const float* __restrict__ Pre, const float* __restrict__ Pim,
               const float2* __restrict__ TW, float* __restrict__ attnW, int* __restrict__ delays) {
  __shared__ float re[LDSN];
  __shared__ float im[LDSN];
  __shared__ float sval[256];
  __shared__ int sidx[256];
  __shared__ int spos[256];
  int bh = blockIdx.x, tid = threadIdx.x;
  for (int e = tid; e < 4096; e += 256) {
    re[IDX(e)] = Pre[bh * 4096 + e];
    im[IDX(e)] = -Pim[bh * 4096 + e];  // conj
  }
  __syncthreads();
  dif_fft(re, im, TW, tid);
  const float SC = 1.0f / 262144.0f;  // 1/(L*Dh)
  float topv[8]; int topi[8];
  for (int pass = 0; pass < 8; ++pass) {
    float bv = -3.4e38f; int bi = 1 << 30; int bp = 0;
    for (int p = tid; p < 4096; p += 256) {
      float v = re[IDX(p)];
      int tau = rev4_12(p);
      if (v > bv || (v == bv && tau < bi)) { bv = v; bi = tau; bp = p; }
    }
    sval[tid] = bv; sidx[tid] = bi; spos[tid] = bp;
    __syncthreads();
    for (int off = 128; off > 0; off >>= 1) {
      if (tid < off) {
        float ov = sval[tid + off]; int oi = sidx[tid + off];
        if (ov > sval[tid] || (ov == sval[tid] && oi < sidx[tid])) {
          sval[tid] = ov; sidx[tid] = oi; spos[tid] = spos[tid + off];
        }
      }
      __syncthreads();
    }
    topv[pass] = sval[0] * SC;
    topi[pass] = sidx[0];
    if (tid == 0) re[IDX(spos[0])] = -3.4e38f;
    __syncthreads();
  }
  if (tid == 0) {
    float mx = topv[0];  // pass 0 = global max
    float ex[8], s = 0.f;
    for (int k = 0; k < 8; ++k) { ex[k] = expf(topv[k] - mx); s += ex[k]; }
    float inv = 1.0f / s;
    for (int k = 0; k < 8; ++k) {
      attnW[bh * 8 + k] = ex[k] * inv;
      delays[bh * 8 + k] = topi[k];
    }
  }
}

// out[b,h,t,:] = sum_k attn_k * V[b,h,(t-d_k)%L,:]; write bf16 into final-GEMM A layout.
__global__ void gather_av(const float* __restrict__ V, const float* __restrict__ attnW,
                          const int* __restrict__ delays, unsigned short* __restrict__ Ahi) {
  int blk = blockIdx.x;
  int bh = blk >> 8, tb = blk & 255;
  int tid = threadIdx.x;
  int tt = tid >> 4, dq = tid & 15;
  int t = (tb << 4) + tt;
  const float4* Vb = (const float4*)(V + (size_t)bh * 4096 * 64);
  float4 acc = make_float4(0.f, 0.f, 0.f, 0.f);
#pragma unroll
  for (int kk = 0; kk < 8; ++kk) {
    float w = attnW[bh * 8 + kk];
    int dl = delays[bh * 8 + kk];
    int row = (t - dl) & 4095;
    float4 x = Vb[row * 16 + dq];
    acc.x += w * x.x; acc.y += w * x.y; acc.z += w * x.z; acc.w += w * x.w;
  }
  int b = bh >> 3, h = bh & 7;
  size_t o = ((size_t)((b << 12) + t)) * 512 + (h << 6) + (dq << 2);
  ushort4 hv;
  hv.x = f2bf(acc.x); hv.y = f2bf(acc.y); hv.z = f2bf(acc.z); hv.w = f2bf(acc.w);
  *(ushort4*)(Ahi + o) = hv;
}

// ---------------- orchestration ----------------
extern "C" void kernel_launch(void* const* d_in, const int* in_sizes, int n_in,
                              void* d_out, int out_size, void* d_ws, size_t ws_size,
                              hipStream_t stream) {
  (void)in_sizes; (void)n_in; (void)out_size; (void)ws_size;
  const float* x_q = (const float*)d_in[0];
  const float* x_kv = (const float*)d_in[1];
  const float* Wq = (const float*)d_in[2];
  const float* bq = (const float*)d_in[3];
  const float* Wk = (const float*)d_in[4];
  const float* bk = (const float*)d_in[5];
  const float* Wv = (const float*)d_in[6];
  const float* bv = (const float*)d_in[7];
  const float* Wo = (const float*)d_in[8];
  const float* bo = (const float*)d_in[9];
  float* out = (float*)d_out;
  char* ws = (char*)d_ws;

  // workspace layout (regions reused over the pipeline; total ~137.1 MiB)
  unsigned short* AqHi  = (unsigned short*)(ws + 0 * MiB);
  unsigned short* AqLo  = (unsigned short*)(ws + 16 * MiB);
  float*          Vbuf  = (float*)(ws + 0 * MiB);          // reuses Aq region after GEMM-Q
  unsigned short* AkvHi = (unsigned short*)(ws + 36 * MiB);
  unsigned short* AkvLo = (unsigned short*)(ws + 52 * MiB);
  unsigned short* Aattn = (unsigned short*)(ws + 36 * MiB); // reuses Akv region after GEMM-V
  unsigned short* WTb   = (unsigned short*)(ws + 68 * MiB); // 8 x 512x512 bf16
  float* QT    = (float*)(ws + 72 * MiB);
  float* KT    = (float*)(ws + 104 * MiB);
  float* PreB  = (float*)(ws + 136 * MiB);
  float* PimB  = (float*)(ws + 136 * MiB + 524288);
  float* attnW = (float*)(ws + 137 * MiB);
  int*   delays = (int*)(ws + 137 * MiB + 4096);
  float2* TW   = (float2*)(ws + 137 * MiB + 8192);

  int n4 = (16384 * 512) / 4;
  conv_split<<<dim3(n4 / 256), dim3(256), 0, stream>>>(x_q, AqHi, AqLo, n4);
  conv_split<<<dim3(n4 / 256), dim3(256), 0, stream>>>(x_kv, AkvHi, AkvLo, n4);
  conv_wt<<<dim3(1024), dim3(256), 0, stream>>>(Wq, WTb + 0 * 262144, WTb + 1 * 262144);
  conv_wt<<<dim3(1024), dim3(256), 0, stream>>>(Wk, WTb + 2 * 262144, WTb + 3 * 262144);
  conv_wt<<<dim3(1024), dim3(256), 0, stream>>>(Wv, WTb + 4 * 262144, WTb + 5 * 262144);
  conv_wt<<<dim3(1024), dim3(256), 0, stream>>>(Wo, WTb + 6 * 262144, WTb + 7 * 262144);
  make_tw<<<dim3(12), dim3(256), 0, stream>>>(TW);
  hipMemsetAsync(PreB, 0, 2 * 524288, stream);

  // Q = x_q @ Wq (bf16x3, -> Q^T layout), K likewise, V plain bf16 (-> (b,h,t,d))
  gemm_bf16<<<dim3(512), dim3(256), 0, stream>>>(AqHi, AqLo, WTb + 0 * 262144, WTb + 1 * 262144, bq, QT, 3, 0);
  gemm_bf16<<<dim3(512), dim3(256), 0, stream>>>(AkvHi, AkvLo, WTb + 2 * 262144, WTb + 3 * 262144, bk, KT, 3, 0);
  gemm_bf16<<<dim3(512), dim3(256), 0, stream>>>(AkvHi, AkvLo, WTb + 4 * 262144, WTb + 5 * 262144, bv, Vbuf, 1, 1);

  fft_corr<<<dim3(512), dim3(256), 0, stream>>>(QT, KT, TW, PreB, PimB);
  ifft_topk<<<dim3(32), dim3(256), 0, stream>>>(PreB, PimB, TW, attnW, delays);
  gather_av<<<dim3(8192), dim3(256), 0, stream>>>(Vbuf, attnW, delays, Aattn);

  // out = gathered @ Wo + bo (plain bf16)
  gemm_bf16<<<dim3(512), dim3(256), 0, stream>>>(Aattn, Aattn, WTb + 6 * 262144, WTb + 7 * 262144, bo, out, 1, 2);
}